// Round 3
// baseline (11970.831 us; speedup 1.0000x reference)
//
#include <hip/hip_runtime.h>
#include <hip/hip_bf16.h>

// LightGCN: x = concat(user_emb, item_emb); 3x [x = segsum(val * x[src] by dst)],
// acc = sum of all 4 x's; out = (acc/4)[u rows].
// R3: 64-node dst-bins. Build = LDS-hist + scan + L2-local binned scatter
// (R2's scatter wrote 619MB due to random 8B stores over 80MB -> 800us).
// SpMV = one block per bin, LDS f32 accumulate (ds_add_f32), x8 gather ILP.

constexpr int SCAN_BS   = 256;
constexpr int BIN_SHIFT = 6;
constexpr int BIN_NODES = 1 << BIN_SHIFT;   // 64 nodes/bin, 16KB LDS acc
constexpr int SPMV_BLOCK = 128;             // 2 waves

__global__ void concat_kernel(const float4* __restrict__ ue, const float4* __restrict__ ie,
                              float4* __restrict__ x, long n_user4, long total4) {
    long i = (long)blockIdx.x * blockDim.x + threadIdx.x;
    long stride = (long)gridDim.x * blockDim.x;
    for (; i < total4; i += stride)
        x[i] = (i < n_user4) ? ue[i] : ie[i - n_user4];
}

// Per-block LDS histogram of dst bins, merged to global once per block.
__global__ void bin_hist_kernel(const int* __restrict__ dst, int* __restrict__ bin_cnt,
                                int n, int nbins) {
    extern __shared__ int lh[];
    for (int j = threadIdx.x; j < nbins; j += blockDim.x) lh[j] = 0;
    __syncthreads();
    int i = blockIdx.x * blockDim.x + threadIdx.x;
    int stride = gridDim.x * blockDim.x;
    for (; i < n; i += stride) atomicAdd(&lh[dst[i] >> BIN_SHIFT], 1);
    __syncthreads();
    for (int j = threadIdx.x; j < nbins; j += blockDim.x) {
        int c = lh[j];
        if (c) atomicAdd(&bin_cnt[j], c);
    }
}

// Per-block exclusive scan (Hillis-Steele in LDS) + per-block totals.
__global__ void scan_blocks_kernel(const int* __restrict__ counts, int* __restrict__ base,
                                   int* __restrict__ blk_sums, int n) {
    __shared__ int tmp[SCAN_BS];
    int tid = threadIdx.x;
    int i = blockIdx.x * SCAN_BS + tid;
    int v = (i < n) ? counts[i] : 0;
    tmp[tid] = v;
    __syncthreads();
    for (int off = 1; off < SCAN_BS; off <<= 1) {
        int t = (tid >= off) ? tmp[tid - off] : 0;
        __syncthreads();
        tmp[tid] += t;
        __syncthreads();
    }
    if (i < n) base[i] = tmp[tid] - v;             // exclusive
    if (tid == SCAN_BS - 1) blk_sums[blockIdx.x] = tmp[tid];
}

__global__ void scan_sums_kernel(int* blk_sums, int nblk) {
    __shared__ int tmp[1024];
    int tid = threadIdx.x;
    int v = (tid < nblk) ? blk_sums[tid] : 0;
    tmp[tid] = v;
    __syncthreads();
    for (int off = 1; off < 1024; off <<= 1) {
        int t = (tid >= off) ? tmp[tid - off] : 0;
        __syncthreads();
        tmp[tid] += t;
        __syncthreads();
    }
    if (tid < nblk) blk_sums[tid] = tmp[tid] - v;  // exclusive
}

__global__ void scan_finalize_kernel(int* __restrict__ base, const int* __restrict__ blk_sums,
                                     int* __restrict__ cursor, int n, int n_edges) {
    int i = blockIdx.x * SCAN_BS + threadIdx.x;
    if (i < n) {
        int r = base[i] + blk_sums[blockIdx.x];
        base[i] = r;
        cursor[i] = r;
    }
    if (i == 0) base[n] = n_edges;
}

// Binned scatter: pack {src | dst_local<<24, val_bits}; writes land within a
// bin's ~34KB region -> L2-local, full-line writebacks (vs 8x inflation in R2).
__global__ void scatter_bin_kernel(const int* __restrict__ src, const int* __restrict__ dst,
                                   const float* __restrict__ val, int* cursor,
                                   int2* __restrict__ bedges, int n) {
    int i = blockIdx.x * blockDim.x + threadIdx.x;
    if (i >= n) return;
    int d = dst[i];
    int bin = d >> BIN_SHIFT;
    int p = atomicAdd(&cursor[bin], 1);
    bedges[p] = make_int2(src[i] | ((d & (BIN_NODES - 1)) << 24), __float_as_int(val[i]));
}

// One block per bin; LDS f32 accumulator rows; lane = feature dim.
// 8 independent gathers in flight per wave; LDS atomicAdd has no return -> no chain.
__global__ __launch_bounds__(SPMV_BLOCK) void spmv_bin_kernel(
        const float* __restrict__ x, float* __restrict__ y,
        const int* __restrict__ bin_base, const int2* __restrict__ bedges, int n_nodes) {
    __shared__ float acc[BIN_NODES * 64];
    int tid  = threadIdx.x;
    int lane = tid & 63;
    int wave = tid >> 6;                       // 0..1
    float4* acc4 = (float4*)acc;
    for (int i = tid; i < BIN_NODES * 16; i += SPMV_BLOCK)
        acc4[i] = make_float4(0.f, 0.f, 0.f, 0.f);
    __syncthreads();

    int bin = blockIdx.x;
    int e0 = bin_base[bin], e1 = bin_base[bin + 1];
    int E = e1 - e0;
    int full = E & ~15;                        // chunks of 16 = 2 waves * 8
    for (int c = wave * 8; c < full; c += 16) {
        int b = e0 + c;
        int2 q0 = bedges[b + 0];
        int2 q1 = bedges[b + 1];
        int2 q2 = bedges[b + 2];
        int2 q3 = bedges[b + 3];
        int2 q4 = bedges[b + 4];
        int2 q5 = bedges[b + 5];
        int2 q6 = bedges[b + 6];
        int2 q7 = bedges[b + 7];
        float g0 = x[(size_t)(q0.x & 0xFFFFFF) * 64 + lane];
        float g1 = x[(size_t)(q1.x & 0xFFFFFF) * 64 + lane];
        float g2 = x[(size_t)(q2.x & 0xFFFFFF) * 64 + lane];
        float g3 = x[(size_t)(q3.x & 0xFFFFFF) * 64 + lane];
        float g4 = x[(size_t)(q4.x & 0xFFFFFF) * 64 + lane];
        float g5 = x[(size_t)(q5.x & 0xFFFFFF) * 64 + lane];
        float g6 = x[(size_t)(q6.x & 0xFFFFFF) * 64 + lane];
        float g7 = x[(size_t)(q7.x & 0xFFFFFF) * 64 + lane];
        atomicAdd(&acc[((unsigned)q0.x >> 24) * 64 + lane], __int_as_float(q0.y) * g0);
        atomicAdd(&acc[((unsigned)q1.x >> 24) * 64 + lane], __int_as_float(q1.y) * g1);
        atomicAdd(&acc[((unsigned)q2.x >> 24) * 64 + lane], __int_as_float(q2.y) * g2);
        atomicAdd(&acc[((unsigned)q3.x >> 24) * 64 + lane], __int_as_float(q3.y) * g3);
        atomicAdd(&acc[((unsigned)q4.x >> 24) * 64 + lane], __int_as_float(q4.y) * g4);
        atomicAdd(&acc[((unsigned)q5.x >> 24) * 64 + lane], __int_as_float(q5.y) * g5);
        atomicAdd(&acc[((unsigned)q6.x >> 24) * 64 + lane], __int_as_float(q6.y) * g6);
        atomicAdd(&acc[((unsigned)q7.x >> 24) * 64 + lane], __int_as_float(q7.y) * g7);
    }
    for (int e = e0 + full + wave; e < e1; e += 2) {
        int2 q = bedges[e];
        atomicAdd(&acc[((unsigned)q.x >> 24) * 64 + lane],
                  __int_as_float(q.y) * x[(size_t)(q.x & 0xFFFFFF) * 64 + lane]);
    }
    __syncthreads();

    int node0 = bin << BIN_SHIFT;
    int nvalid = min(BIN_NODES, n_nodes - node0);
    float4* y4 = (float4*)(y + (size_t)node0 * 64);
    for (int i = tid; i < nvalid * 16; i += SPMV_BLOCK)
        y4[i] = acc4[i];
}

__global__ void out_accum_kernel(const float* __restrict__ x, const int* __restrict__ u,
                                 float* __restrict__ out, int first) {
    int i = blockIdx.x;
    int lane = threadIdx.x;
    float v = 0.25f * x[(size_t)u[i] * 64 + lane];
    if (first) out[(size_t)i * 64 + lane] = v;
    else       out[(size_t)i * 64 + lane] += v;
}

// Fallback if workspace is too small: edge-parallel atomic scatter.
__global__ void spmv_atomic_kernel(const float* __restrict__ x, float* y,
                                   const int* __restrict__ src, const int* __restrict__ dst,
                                   const float* __restrict__ val, int n_edges) {
    int lane = threadIdx.x & 63;
    int e = blockIdx.x * (blockDim.x >> 6) + (threadIdx.x >> 6);
    if (e >= n_edges) return;
    float v = val[e];
    atomicAdd(&y[(size_t)dst[e] * 64 + lane], v * x[(size_t)src[e] * 64 + lane]);
}

extern "C" void kernel_launch(void* const* d_in, const int* in_sizes, int n_in,
                              void* d_out, int out_size, void* d_ws, size_t ws_size,
                              hipStream_t stream) {
    const float* user_emb = (const float*)d_in[0];
    const float* item_emb = (const float*)d_in[1];
    const int*   edge_src = (const int*)d_in[2];
    const int*   edge_dst = (const int*)d_in[3];
    const float* edge_val = (const float*)d_in[4];
    const int*   u        = (const int*)d_in[5];
    float* out = (float*)d_out;

    const int n_users = in_sizes[0] / 64;
    const int n_items = in_sizes[1] / 64;
    const int n_nodes = n_users + n_items;
    const int n_edges = in_sizes[2];
    const int n_u     = in_sizes[5];
    const int nbins   = (n_nodes + BIN_NODES - 1) >> BIN_SHIFT;   // 2344

    const size_t xbytes = (size_t)n_nodes * 64 * sizeof(float);
    char* w = (char*)d_ws;
    float* x_a = (float*)w; w += xbytes;
    float* x_b = (float*)w; w += xbytes;

    long n_user4 = (long)n_users * 16;
    long total4  = (long)n_nodes * 16;
    concat_kernel<<<2048, 256, 0, stream>>>((const float4*)user_emb, (const float4*)item_emb,
                                            (float4*)x_a, n_user4, total4);

    const size_t need = 2 * xbytes + (size_t)n_edges * 8
                      + ((size_t)nbins * 2 + 1 + 1024) * 4 + 8192;
    const bool use_bins = (ws_size >= need) && (n_nodes < (1 << 24));

    float* cur = x_a;
    float* nxt = x_b;

    out_accum_kernel<<<n_u, 64, 0, stream>>>(cur, u, out, 1);

    if (use_bins) {
        int2* bedges   = (int2*)w;  w += (size_t)n_edges * 8;
        int*  bin_base = (int*)w;   w += ((size_t)nbins + 1) * 4;
        int*  cursor   = (int*)w;   w += (size_t)nbins * 4;
        int*  blk_sums = (int*)w;

        hipMemsetAsync(cursor, 0, (size_t)nbins * 4, stream);
        bin_hist_kernel<<<1024, 256, (size_t)nbins * 4, stream>>>(edge_dst, cursor,
                                                                  n_edges, nbins);
        int nblk = (nbins + SCAN_BS - 1) / SCAN_BS;   // 10 for this shape
        scan_blocks_kernel<<<nblk, SCAN_BS, 0, stream>>>(cursor, bin_base, blk_sums, nbins);
        scan_sums_kernel<<<1, 1024, 0, stream>>>(blk_sums, nblk);
        scan_finalize_kernel<<<nblk, SCAN_BS, 0, stream>>>(bin_base, blk_sums, cursor,
                                                           nbins, n_edges);
        scatter_bin_kernel<<<(n_edges + 255) / 256, 256, 0, stream>>>(edge_src, edge_dst,
                                                                      edge_val, cursor,
                                                                      bedges, n_edges);
        for (int l = 0; l < 3; ++l) {
            spmv_bin_kernel<<<nbins, SPMV_BLOCK, 0, stream>>>(cur, nxt, bin_base,
                                                              bedges, n_nodes);
            out_accum_kernel<<<n_u, 64, 0, stream>>>(nxt, u, out, 0);
            float* t = cur; cur = nxt; nxt = t;
        }
    } else {
        for (int l = 0; l < 3; ++l) {
            hipMemsetAsync(nxt, 0, xbytes, stream);
            spmv_atomic_kernel<<<(n_edges + 3) / 4, 256, 0, stream>>>(cur, nxt, edge_src,
                                                                      edge_dst, edge_val, n_edges);
            out_accum_kernel<<<n_u, 64, 0, stream>>>(nxt, u, out, 0);
            float* t = cur; cur = nxt; nxt = t;
        }
    }
}

// Round 4
// 2065.853 us; speedup vs baseline: 5.7946x; 5.7946x over previous
//
#include <hip/hip_runtime.h>
#include <hip/hip_bf16.h>

// LightGCN R4: per-node wave spmv (R2 structure, proven; R3's bin-spmv lost 10x
// TLP -> latency stall) with bf16 feature storage (halves gather lines + x
// footprint), and a two-pass scatter build:
//   pass1: LDS-aggregated counting scatter into 74 coarse bins (2048 nodes) --
//          74 write frontiers, full-line writebacks (R2 single-pass scatter
//          wrote 619MB for an 80MB CSR).
//   pass2: exact per-node placement; writes confined to ~1.1MB bin regions.

constexpr int SCAN_BS  = 256;
constexpr int CSHIFT   = 11;                  // coarse bin = 2048 nodes
constexpr int CMASK    = (1 << CSHIFT) - 1;
constexpr int MAXC     = 128;                 // max coarse bins (LDS arrays)
constexpr int P1_EPT   = 16;
constexpr int P1_BS    = 256;
constexpr int P1_CHUNK = P1_BS * P1_EPT;      // 4096 edges/block
constexpr int P2_SEGS  = 32;

__device__ __forceinline__ unsigned short f2bf(float f) {
    unsigned u = __float_as_uint(f);
    u += 0x7FFFu + ((u >> 16) & 1u);          // round-to-nearest-even
    return (unsigned short)(u >> 16);
}
__device__ __forceinline__ float bf2f(unsigned short us) {
    return __uint_as_float((unsigned)us << 16);
}

__global__ void concat_bf16_kernel(const float4* __restrict__ ue, const float4* __restrict__ ie,
                                   ushort4* __restrict__ x, long n_user4, long total4) {
    long i = (long)blockIdx.x * blockDim.x + threadIdx.x;
    long stride = (long)gridDim.x * blockDim.x;
    for (; i < total4; i += stride) {
        float4 v = (i < n_user4) ? ue[i] : ie[i - n_user4];
        ushort4 o;
        o.x = f2bf(v.x); o.y = f2bf(v.y); o.z = f2bf(v.z); o.w = f2bf(v.w);
        x[i] = o;
    }
}

__global__ void hist_kernel(const int* __restrict__ dst, int* counts, int n) {
    int i = blockIdx.x * blockDim.x + threadIdx.x;
    int stride = gridDim.x * blockDim.x;
    for (; i < n; i += stride) atomicAdd(&counts[dst[i]], 1);
}

// Per-block exclusive scan (Hillis-Steele in LDS) + per-block totals.
__global__ void scan_blocks_kernel(const int* __restrict__ counts, int* __restrict__ base,
                                   int* __restrict__ blk_sums, int n) {
    __shared__ int tmp[SCAN_BS];
    int tid = threadIdx.x;
    int i = blockIdx.x * SCAN_BS + tid;
    int v = (i < n) ? counts[i] : 0;
    tmp[tid] = v;
    __syncthreads();
    for (int off = 1; off < SCAN_BS; off <<= 1) {
        int t = (tid >= off) ? tmp[tid - off] : 0;
        __syncthreads();
        tmp[tid] += t;
        __syncthreads();
    }
    if (i < n) base[i] = tmp[tid] - v;             // exclusive
    if (tid == SCAN_BS - 1) blk_sums[blockIdx.x] = tmp[tid];
}

__global__ void scan_sums_kernel(int* blk_sums, int nblk) {
    __shared__ int tmp[1024];
    int tid = threadIdx.x;
    int v = (tid < nblk) ? blk_sums[tid] : 0;
    tmp[tid] = v;
    __syncthreads();
    for (int off = 1; off < 1024; off <<= 1) {
        int t = (tid >= off) ? tmp[tid - off] : 0;
        __syncthreads();
        tmp[tid] += t;
        __syncthreads();
    }
    if (tid < nblk) blk_sums[tid] = tmp[tid] - v;  // exclusive
}

__global__ void scan_finalize_kernel(int* __restrict__ row_ptr, const int* __restrict__ blk_sums,
                                     int* __restrict__ node_cursor, int* __restrict__ gcursor,
                                     int n, int n_edges) {
    int i = blockIdx.x * SCAN_BS + threadIdx.x;
    if (i < n) {
        int r = row_ptr[i] + blk_sums[blockIdx.x];
        row_ptr[i] = r;
        node_cursor[i] = r;
        if ((i & CMASK) == 0) gcursor[i >> CSHIFT] = r;  // coarse bin base
    }
    if (i == 0) row_ptr[n] = n_edges;
}

// Pass 1: counting scatter into coarse bins. Per-block LDS hist gives each edge
// a block-local rank; one global atomic per (block,bin) instead of per edge.
// Writes land at 74 advancing frontiers -> full-line writebacks.
__global__ __launch_bounds__(P1_BS) void pass1_kernel(
        const int* __restrict__ src, const int* __restrict__ dst,
        const float* __restrict__ val, int* gcursor, int2* __restrict__ tmp,
        int n, int nbc) {
    __shared__ int lh[MAXC];
    __shared__ int lbase[MAXC];
    int tid = threadIdx.x;
    int base = blockIdx.x * P1_CHUNK;
    for (int j = tid; j < nbc; j += P1_BS) lh[j] = 0;
    __syncthreads();
    int dreg[P1_EPT], rreg[P1_EPT];
#pragma unroll
    for (int k = 0; k < P1_EPT; ++k) {
        int i = base + k * P1_BS + tid;
        if (i < n) {
            int d = dst[i];
            dreg[k] = d;
            rreg[k] = atomicAdd(&lh[d >> CSHIFT], 1);
        } else dreg[k] = -1;
    }
    __syncthreads();
    for (int j = tid; j < nbc; j += P1_BS) {
        int c = lh[j];
        lbase[j] = c ? atomicAdd(&gcursor[j], c) : 0;
    }
    __syncthreads();
#pragma unroll
    for (int k = 0; k < P1_EPT; ++k) {
        int d = dreg[k];
        if (d >= 0) {
            int i = base + k * P1_BS + tid;
            int p = lbase[d >> CSHIFT] + rreg[k];
            tmp[p] = make_int2(src[i] | ((d & CMASK) << 21), __float_as_int(val[i]));
        }
    }
}

// Pass 2: within each coarse bin, place edges at exact per-node positions.
// Random writes confined to the bin's ~1.1MB region -> L2-absorbed.
__global__ void pass2_kernel(const int2* __restrict__ tmp, const int* __restrict__ row_ptr,
                             int* node_cursor, int2* __restrict__ csr, int n_nodes) {
    int bin = blockIdx.x >> 5;
    int seg = blockIdx.x & (P2_SEGS - 1);
    int nb0 = bin << CSHIFT;
    int nb1 = min(nb0 + (1 << CSHIFT), n_nodes);
    int e0 = row_ptr[nb0];
    int e1 = row_ptr[nb1];
    int len = e1 - e0;
    int s0 = e0 + (int)((long)len * seg / P2_SEGS);
    int s1 = e0 + (int)((long)len * (seg + 1) / P2_SEGS);
    for (int i = s0 + threadIdx.x; i < s1; i += blockDim.x) {
        int2 q = tmp[i];
        int node = nb0 + (int)((unsigned)q.x >> 21);
        int p = atomicAdd(&node_cursor[node], 1);
        csr[p] = make_int2(q.x & 0x1FFFFF, q.y);
    }
}

// One wave per node; lane = feature dim; x8 independent bf16 gathers in flight.
__global__ __launch_bounds__(256) void spmv_kernel(
        const unsigned short* __restrict__ x, unsigned short* __restrict__ y,
        const int* __restrict__ row_ptr, const int2* __restrict__ csr, int n_nodes) {
    int lane = threadIdx.x & 63;
    int node = blockIdx.x * 4 + (threadIdx.x >> 6);
    if (node >= n_nodes) return;
    int e0 = row_ptr[node];
    int e1 = row_ptr[node + 1];
    float a0 = 0.f, a1 = 0.f, a2 = 0.f, a3 = 0.f;
    float a4 = 0.f, a5 = 0.f, a6 = 0.f, a7 = 0.f;
    int e = e0;
    for (; e + 8 <= e1; e += 8) {
        int2 q0 = csr[e + 0];
        int2 q1 = csr[e + 1];
        int2 q2 = csr[e + 2];
        int2 q3 = csr[e + 3];
        int2 q4 = csr[e + 4];
        int2 q5 = csr[e + 5];
        int2 q6 = csr[e + 6];
        int2 q7 = csr[e + 7];
        float g0 = bf2f(x[((unsigned)q0.x << 6) + lane]);
        float g1 = bf2f(x[((unsigned)q1.x << 6) + lane]);
        float g2 = bf2f(x[((unsigned)q2.x << 6) + lane]);
        float g3 = bf2f(x[((unsigned)q3.x << 6) + lane]);
        float g4 = bf2f(x[((unsigned)q4.x << 6) + lane]);
        float g5 = bf2f(x[((unsigned)q5.x << 6) + lane]);
        float g6 = bf2f(x[((unsigned)q6.x << 6) + lane]);
        float g7 = bf2f(x[((unsigned)q7.x << 6) + lane]);
        a0 = fmaf(__int_as_float(q0.y), g0, a0);
        a1 = fmaf(__int_as_float(q1.y), g1, a1);
        a2 = fmaf(__int_as_float(q2.y), g2, a2);
        a3 = fmaf(__int_as_float(q3.y), g3, a3);
        a4 = fmaf(__int_as_float(q4.y), g4, a4);
        a5 = fmaf(__int_as_float(q5.y), g5, a5);
        a6 = fmaf(__int_as_float(q6.y), g6, a6);
        a7 = fmaf(__int_as_float(q7.y), g7, a7);
    }
    for (; e < e1; ++e) {
        int2 q = csr[e];
        a0 = fmaf(__int_as_float(q.y), bf2f(x[((unsigned)q.x << 6) + lane]), a0);
    }
    float s = ((a0 + a1) + (a2 + a3)) + ((a4 + a5) + (a6 + a7));
    y[((unsigned)node << 6) + lane] = f2bf(s);
}

__global__ void out_first_kernel(const float* __restrict__ ue, const int* __restrict__ u,
                                 float* __restrict__ out) {
    int i = blockIdx.x;
    int lane = threadIdx.x;
    out[(size_t)i * 64 + lane] = 0.25f * ue[(size_t)u[i] * 64 + lane];
}

__global__ void out_accum_kernel(const unsigned short* __restrict__ x, const int* __restrict__ u,
                                 float* __restrict__ out) {
    int i = blockIdx.x;
    int lane = threadIdx.x;
    out[(size_t)i * 64 + lane] += 0.25f * bf2f(x[((unsigned)u[i] << 6) + lane]);
}

// ---- f32 fallback path (tiny ws) ----
__global__ void concat_kernel(const float4* __restrict__ ue, const float4* __restrict__ ie,
                              float4* __restrict__ x, long n_user4, long total4) {
    long i = (long)blockIdx.x * blockDim.x + threadIdx.x;
    long stride = (long)gridDim.x * blockDim.x;
    for (; i < total4; i += stride)
        x[i] = (i < n_user4) ? ue[i] : ie[i - n_user4];
}
__global__ void spmv_atomic_kernel(const float* __restrict__ x, float* y,
                                   const int* __restrict__ src, const int* __restrict__ dst,
                                   const float* __restrict__ val, int n_edges) {
    int lane = threadIdx.x & 63;
    int e = blockIdx.x * (blockDim.x >> 6) + (threadIdx.x >> 6);
    if (e >= n_edges) return;
    float v = val[e];
    atomicAdd(&y[(size_t)dst[e] * 64 + lane], v * x[(size_t)src[e] * 64 + lane]);
}
__global__ void out_accum_f32_kernel(const float* __restrict__ x, const int* __restrict__ u,
                                     float* __restrict__ out, int first) {
    int i = blockIdx.x;
    int lane = threadIdx.x;
    float v = 0.25f * x[(size_t)u[i] * 64 + lane];
    if (first) out[(size_t)i * 64 + lane] = v;
    else       out[(size_t)i * 64 + lane] += v;
}

extern "C" void kernel_launch(void* const* d_in, const int* in_sizes, int n_in,
                              void* d_out, int out_size, void* d_ws, size_t ws_size,
                              hipStream_t stream) {
    const float* user_emb = (const float*)d_in[0];
    const float* item_emb = (const float*)d_in[1];
    const int*   edge_src = (const int*)d_in[2];
    const int*   edge_dst = (const int*)d_in[3];
    const float* edge_val = (const float*)d_in[4];
    const int*   u        = (const int*)d_in[5];
    float* out = (float*)d_out;

    const int n_users = in_sizes[0] / 64;
    const int n_items = in_sizes[1] / 64;
    const int n_nodes = n_users + n_items;
    const int n_edges = in_sizes[2];
    const int n_u     = in_sizes[5];
    const int nbc     = (n_nodes + CMASK) >> CSHIFT;     // 74 for this shape

    const size_t xbytes_bf = (size_t)n_nodes * 64 * 2;   // 19.2 MB
    const size_t ebytes    = (size_t)n_edges * 8;        // 80 MB
    const size_t tmp_bytes = ebytes > 2 * xbytes_bf ? ebytes : 2 * xbytes_bf;

    const size_t need = ebytes + tmp_bytes + ((size_t)n_nodes * 2 + 1) * 4
                      + (MAXC + 1024) * 4 + 8192;
    const bool use_main = (ws_size >= need) && (n_nodes < (1 << 21)) && (nbc <= MAXC);

    long n_user4 = (long)n_users * 16;
    long total4  = (long)n_nodes * 16;

    if (use_main) {
        char* w = (char*)d_ws;
        int2* csr = (int2*)w;        w += ebytes;
        int2* tmp = (int2*)w;                               // pass1 output
        unsigned short* x_a = (unsigned short*)tmp;         // alias: tmp dead after pass2
        unsigned short* x_b = x_a + (size_t)n_nodes * 64;
        w += tmp_bytes;
        int* row_ptr     = (int*)w;  w += ((size_t)n_nodes + 1) * 4;
        int* node_cursor = (int*)w;  w += (size_t)n_nodes * 4;
        int* gcursor     = (int*)w;  w += MAXC * 4;
        int* blk_sums    = (int*)w;

        // ---- build per-node CSR (two-pass) ----
        hipMemsetAsync(node_cursor, 0, (size_t)n_nodes * 4, stream);
        hist_kernel<<<2048, 256, 0, stream>>>(edge_dst, node_cursor, n_edges);
        int nblk = (n_nodes + SCAN_BS - 1) / SCAN_BS;       // 586 (<=1024)
        scan_blocks_kernel<<<nblk, SCAN_BS, 0, stream>>>(node_cursor, row_ptr, blk_sums, n_nodes);
        scan_sums_kernel<<<1, 1024, 0, stream>>>(blk_sums, nblk);
        scan_finalize_kernel<<<nblk, SCAN_BS, 0, stream>>>(row_ptr, blk_sums, node_cursor,
                                                           gcursor, n_nodes, n_edges);
        pass1_kernel<<<(n_edges + P1_CHUNK - 1) / P1_CHUNK, P1_BS, 0, stream>>>(
            edge_src, edge_dst, edge_val, gcursor, tmp, n_edges, nbc);
        pass2_kernel<<<nbc * P2_SEGS, 256, 0, stream>>>(tmp, row_ptr, node_cursor,
                                                        csr, n_nodes);

        // ---- features (bf16) + propagate ----
        concat_bf16_kernel<<<2048, 256, 0, stream>>>((const float4*)user_emb,
                                                     (const float4*)item_emb,
                                                     (ushort4*)x_a, n_user4, total4);
        out_first_kernel<<<n_u, 64, 0, stream>>>(user_emb, u, out);

        unsigned short* cur = x_a;
        unsigned short* nxt = x_b;
        for (int l = 0; l < 3; ++l) {
            spmv_kernel<<<(n_nodes + 3) / 4, 256, 0, stream>>>(cur, nxt, row_ptr, csr, n_nodes);
            out_accum_kernel<<<n_u, 64, 0, stream>>>(nxt, u, out);
            unsigned short* t = cur; cur = nxt; nxt = t;
        }
    } else {
        const size_t xbytes = (size_t)n_nodes * 64 * 4;
        char* w = (char*)d_ws;
        float* x_a = (float*)w; w += xbytes;
        float* x_b = (float*)w;
        concat_kernel<<<2048, 256, 0, stream>>>((const float4*)user_emb, (const float4*)item_emb,
                                                (float4*)x_a, n_user4, total4);
        out_accum_f32_kernel<<<n_u, 64, 0, stream>>>(x_a, u, out, 1);
        float* cur = x_a;
        float* nxt = x_b;
        for (int l = 0; l < 3; ++l) {
            hipMemsetAsync(nxt, 0, xbytes, stream);
            spmv_atomic_kernel<<<(n_edges + 3) / 4, 256, 0, stream>>>(cur, nxt, edge_src,
                                                                      edge_dst, edge_val, n_edges);
            out_accum_f32_kernel<<<n_u, 64, 0, stream>>>(nxt, u, out, 0);
            float* t = cur; cur = nxt; nxt = t;
        }
    }
}

// Round 5
// 1508.038 us; speedup vs baseline: 7.9380x; 1.3699x over previous
//
#include <hip/hip_runtime.h>
#include <hip/hip_bf16.h>

// LightGCN R5: per-node wave spmv (bf16 x, f32 acc) + 3-level frontier scatter:
//   pass1 : edges -> 74 coarse bins (2048 nodes). LDS hist, ~440B frontier chunks.
//   pass2a: coarse bin -> 32 sub-bins (64 nodes). LDS hist[32], ~1KB frontier chunks.
//   pass2b: sub-bin -> exact node order via LDS cursors + 64KB LDS staging,
//           flushed coalesced. (R4's single random-scatter pass2 wrote 584MB
//           for an 80MB CSR -> 670us: XCD L2s thrashed by 8B writes over 80MB.)

constexpr int SCAN_BS  = 256;
constexpr int CSHIFT   = 11;                  // coarse bin = 2048 nodes
constexpr int CMASK    = (1 << CSHIFT) - 1;
constexpr int MAXC     = 128;                 // max coarse bins
constexpr int P1_EPT   = 16;
constexpr int P1_BS    = 256;
constexpr int P1_CHUNK = P1_BS * P1_EPT;      // 4096 edges/block
constexpr int P2A_SEGS = 32;
constexpr int STAGE_CAP = 8192;               // 64KB int2 staging (avg subbin ~4.3K)

__device__ __forceinline__ unsigned short f2bf(float f) {
    unsigned u = __float_as_uint(f);
    u += 0x7FFFu + ((u >> 16) & 1u);          // round-to-nearest-even
    return (unsigned short)(u >> 16);
}
__device__ __forceinline__ float bf2f(unsigned short us) {
    return __uint_as_float((unsigned)us << 16);
}

__global__ void concat_bf16_kernel(const float4* __restrict__ ue, const float4* __restrict__ ie,
                                   ushort4* __restrict__ x, long n_user4, long total4) {
    long i = (long)blockIdx.x * blockDim.x + threadIdx.x;
    long stride = (long)gridDim.x * blockDim.x;
    for (; i < total4; i += stride) {
        float4 v = (i < n_user4) ? ue[i] : ie[i - n_user4];
        ushort4 o;
        o.x = f2bf(v.x); o.y = f2bf(v.y); o.z = f2bf(v.z); o.w = f2bf(v.w);
        x[i] = o;
    }
}

__global__ void hist_kernel(const int* __restrict__ dst, int* counts, int n) {
    int i = blockIdx.x * blockDim.x + threadIdx.x;
    int stride = gridDim.x * blockDim.x;
    for (; i < n; i += stride) atomicAdd(&counts[dst[i]], 1);
}

__global__ void scan_blocks_kernel(const int* __restrict__ counts, int* __restrict__ base,
                                   int* __restrict__ blk_sums, int n) {
    __shared__ int tmp[SCAN_BS];
    int tid = threadIdx.x;
    int i = blockIdx.x * SCAN_BS + tid;
    int v = (i < n) ? counts[i] : 0;
    tmp[tid] = v;
    __syncthreads();
    for (int off = 1; off < SCAN_BS; off <<= 1) {
        int t = (tid >= off) ? tmp[tid - off] : 0;
        __syncthreads();
        tmp[tid] += t;
        __syncthreads();
    }
    if (i < n) base[i] = tmp[tid] - v;             // exclusive
    if (tid == SCAN_BS - 1) blk_sums[blockIdx.x] = tmp[tid];
}

__global__ void scan_sums_kernel(int* blk_sums, int nblk) {
    __shared__ int tmp[1024];
    int tid = threadIdx.x;
    int v = (tid < nblk) ? blk_sums[tid] : 0;
    tmp[tid] = v;
    __syncthreads();
    for (int off = 1; off < 1024; off <<= 1) {
        int t = (tid >= off) ? tmp[tid - off] : 0;
        __syncthreads();
        tmp[tid] += t;
        __syncthreads();
    }
    if (tid < nblk) blk_sums[tid] = tmp[tid] - v;  // exclusive
}

__global__ void scan_finalize_kernel(int* __restrict__ row_ptr, const int* __restrict__ blk_sums,
                                     int* __restrict__ gcur_c, int* __restrict__ gcur_s,
                                     int n, int n_edges) {
    int i = blockIdx.x * SCAN_BS + threadIdx.x;
    if (i < n) {
        int r = row_ptr[i] + blk_sums[blockIdx.x];
        row_ptr[i] = r;
        if ((i & CMASK) == 0) gcur_c[i >> CSHIFT] = r;   // coarse-bin cursor
        if ((i & 63) == 0)    gcur_s[i >> 6]      = r;   // sub-bin cursor
    }
    if (i == 0) row_ptr[n] = n_edges;
}

// Pass 1: counting scatter into coarse bins; block-local LDS hist -> one global
// atomic per (block,bin); chunk writes (~440B) advance 74 frontiers.
__global__ __launch_bounds__(P1_BS) void pass1_kernel(
        const int* __restrict__ src, const int* __restrict__ dst,
        const float* __restrict__ val, int* gcur_c, int2* __restrict__ bufA,
        int n, int nbc) {
    __shared__ int lh[MAXC];
    __shared__ int lbase[MAXC];
    int tid = threadIdx.x;
    int base = blockIdx.x * P1_CHUNK;
    for (int j = tid; j < nbc; j += P1_BS) lh[j] = 0;
    __syncthreads();
    int dreg[P1_EPT], rreg[P1_EPT];
#pragma unroll
    for (int k = 0; k < P1_EPT; ++k) {
        int i = base + k * P1_BS + tid;
        if (i < n) {
            int d = dst[i];
            dreg[k] = d;
            rreg[k] = atomicAdd(&lh[d >> CSHIFT], 1);
        } else dreg[k] = -1;
    }
    __syncthreads();
    for (int j = tid; j < nbc; j += P1_BS) {
        int c = lh[j];
        lbase[j] = c ? atomicAdd(&gcur_c[j], c) : 0;
    }
    __syncthreads();
#pragma unroll
    for (int k = 0; k < P1_EPT; ++k) {
        int d = dreg[k];
        if (d >= 0) {
            int i = base + k * P1_BS + tid;
            int p = lbase[d >> CSHIFT] + rreg[k];
            bufA[p] = make_int2(src[i] | ((d & CMASK) << 21), __float_as_int(val[i]));
        }
    }
}

// Pass 2a: coarse bin -> 32 sub-bins of 64 nodes. Per-segment LDS hist, global
// frontier claim, ~1KB chunk writes at 2368 frontiers.
__global__ __launch_bounds__(256) void pass2a_kernel(
        const int2* __restrict__ bufA, const int* __restrict__ row_ptr,
        int* gcur_s, int2* __restrict__ bufB, int n_nodes) {
    __shared__ int lh[32], lbase[32], lrank[32];
    int bin = blockIdx.x >> 5;
    int seg = blockIdx.x & (P2A_SEGS - 1);
    int tid = threadIdx.x;
    int nb0 = bin << CSHIFT;
    int nb1 = min(nb0 + (1 << CSHIFT), n_nodes);
    int e0 = row_ptr[nb0], e1 = row_ptr[nb1];
    int len = e1 - e0;
    int s0 = e0 + (int)((long)len * seg / P2A_SEGS);
    int s1 = e0 + (int)((long)len * (seg + 1) / P2A_SEGS);
    if (tid < 32) { lh[tid] = 0; lrank[tid] = 0; }
    __syncthreads();
#pragma unroll 4
    for (int i = s0 + tid; i < s1; i += 256)
        atomicAdd(&lh[((unsigned)bufA[i].x >> 21) >> 6], 1);
    __syncthreads();
    if (tid < 32) {
        int c = lh[tid];
        lbase[tid] = c ? atomicAdd(&gcur_s[(bin << 5) + tid], c) : 0;
    }
    __syncthreads();
#pragma unroll 4
    for (int i = s0 + tid; i < s1; i += 256) {
        int2 q = bufA[i];                       // second read: L2-hot
        int j = ((unsigned)q.x >> 21) >> 6;
        int p = lbase[j] + atomicAdd(&lrank[j], 1);
        bufB[p] = q;
    }
}

// Pass 2b: one block per 64-node sub-bin; LDS cursors (init from row_ptr) rank
// edges into a 64KB LDS staging buffer, flushed coalesced. Zero write inflation.
__global__ __launch_bounds__(256) void pass2b_kernel(
        const int2* __restrict__ bufB, const int* __restrict__ row_ptr,
        int2* __restrict__ csr, int n_nodes) {
    __shared__ int2 stage[STAGE_CAP];
    __shared__ int cur[64];
    int b = blockIdx.x;
    int tid = threadIdx.x;
    int node0 = b << 6;
    int nend = min(node0 + 64, n_nodes);
    int e0 = row_ptr[node0];
    int e1 = row_ptr[nend];
    if (tid < 64) {
        int idx = node0 + tid;
        cur[tid] = ((idx < nend) ? row_ptr[idx] : e1) - e0;
    }
    __syncthreads();
#pragma unroll 4
    for (int i = e0 + tid; i < e1; i += 256) {
        int2 q = bufB[i];
        int nl = ((unsigned)q.x >> 21) & 63;
        int r = atomicAdd(&cur[nl], 1);
        int2 v = make_int2(q.x & 0x1FFFFF, q.y);
        if (r < STAGE_CAP) stage[r] = v;
        else csr[(size_t)e0 + r] = v;           // overflow fallback (rare)
    }
    __syncthreads();
    int lim = min(e1 - e0, STAGE_CAP);
    for (int i = tid; i < lim; i += 256)
        csr[(size_t)e0 + i] = stage[i];
}

// One wave per node; lane = feature dim; x8 independent bf16 gathers in flight.
__global__ __launch_bounds__(256) void spmv_kernel(
        const unsigned short* __restrict__ x, unsigned short* __restrict__ y,
        const int* __restrict__ row_ptr, const int2* __restrict__ csr, int n_nodes) {
    int lane = threadIdx.x & 63;
    int node = blockIdx.x * 4 + (threadIdx.x >> 6);
    if (node >= n_nodes) return;
    int e0 = row_ptr[node];
    int e1 = row_ptr[node + 1];
    float a0 = 0.f, a1 = 0.f, a2 = 0.f, a3 = 0.f;
    float a4 = 0.f, a5 = 0.f, a6 = 0.f, a7 = 0.f;
    int e = e0;
    for (; e + 8 <= e1; e += 8) {
        int2 q0 = csr[e + 0];
        int2 q1 = csr[e + 1];
        int2 q2 = csr[e + 2];
        int2 q3 = csr[e + 3];
        int2 q4 = csr[e + 4];
        int2 q5 = csr[e + 5];
        int2 q6 = csr[e + 6];
        int2 q7 = csr[e + 7];
        float g0 = bf2f(x[((unsigned)q0.x << 6) + lane]);
        float g1 = bf2f(x[((unsigned)q1.x << 6) + lane]);
        float g2 = bf2f(x[((unsigned)q2.x << 6) + lane]);
        float g3 = bf2f(x[((unsigned)q3.x << 6) + lane]);
        float g4 = bf2f(x[((unsigned)q4.x << 6) + lane]);
        float g5 = bf2f(x[((unsigned)q5.x << 6) + lane]);
        float g6 = bf2f(x[((unsigned)q6.x << 6) + lane]);
        float g7 = bf2f(x[((unsigned)q7.x << 6) + lane]);
        a0 = fmaf(__int_as_float(q0.y), g0, a0);
        a1 = fmaf(__int_as_float(q1.y), g1, a1);
        a2 = fmaf(__int_as_float(q2.y), g2, a2);
        a3 = fmaf(__int_as_float(q3.y), g3, a3);
        a4 = fmaf(__int_as_float(q4.y), g4, a4);
        a5 = fmaf(__int_as_float(q5.y), g5, a5);
        a6 = fmaf(__int_as_float(q6.y), g6, a6);
        a7 = fmaf(__int_as_float(q7.y), g7, a7);
    }
    for (; e < e1; ++e) {
        int2 q = csr[e];
        a0 = fmaf(__int_as_float(q.y), bf2f(x[((unsigned)q.x << 6) + lane]), a0);
    }
    float s = ((a0 + a1) + (a2 + a3)) + ((a4 + a5) + (a6 + a7));
    y[((unsigned)node << 6) + lane] = f2bf(s);
}

__global__ void out_first_kernel(const float* __restrict__ ue, const int* __restrict__ u,
                                 float* __restrict__ out) {
    int i = blockIdx.x;
    int lane = threadIdx.x;
    out[(size_t)i * 64 + lane] = 0.25f * ue[(size_t)u[i] * 64 + lane];
}

__global__ void out_accum_kernel(const unsigned short* __restrict__ x, const int* __restrict__ u,
                                 float* __restrict__ out) {
    int i = blockIdx.x;
    int lane = threadIdx.x;
    out[(size_t)i * 64 + lane] += 0.25f * bf2f(x[((unsigned)u[i] << 6) + lane]);
}

// ---- f32 fallback path (tiny ws) ----
__global__ void concat_kernel(const float4* __restrict__ ue, const float4* __restrict__ ie,
                              float4* __restrict__ x, long n_user4, long total4) {
    long i = (long)blockIdx.x * blockDim.x + threadIdx.x;
    long stride = (long)gridDim.x * blockDim.x;
    for (; i < total4; i += stride)
        x[i] = (i < n_user4) ? ue[i] : ie[i - n_user4];
}
__global__ void spmv_atomic_kernel(const float* __restrict__ x, float* y,
                                   const int* __restrict__ src, const int* __restrict__ dst,
                                   const float* __restrict__ val, int n_edges) {
    int lane = threadIdx.x & 63;
    int e = blockIdx.x * (blockDim.x >> 6) + (threadIdx.x >> 6);
    if (e >= n_edges) return;
    float v = val[e];
    atomicAdd(&y[(size_t)dst[e] * 64 + lane], v * x[(size_t)src[e] * 64 + lane]);
}
__global__ void out_accum_f32_kernel(const float* __restrict__ x, const int* __restrict__ u,
                                     float* __restrict__ out, int first) {
    int i = blockIdx.x;
    int lane = threadIdx.x;
    float v = 0.25f * x[(size_t)u[i] * 64 + lane];
    if (first) out[(size_t)i * 64 + lane] = v;
    else       out[(size_t)i * 64 + lane] += v;
}

extern "C" void kernel_launch(void* const* d_in, const int* in_sizes, int n_in,
                              void* d_out, int out_size, void* d_ws, size_t ws_size,
                              hipStream_t stream) {
    const float* user_emb = (const float*)d_in[0];
    const float* item_emb = (const float*)d_in[1];
    const int*   edge_src = (const int*)d_in[2];
    const int*   edge_dst = (const int*)d_in[3];
    const float* edge_val = (const float*)d_in[4];
    const int*   u        = (const int*)d_in[5];
    float* out = (float*)d_out;

    const int n_users = in_sizes[0] / 64;
    const int n_items = in_sizes[1] / 64;
    const int n_nodes = n_users + n_items;
    const int n_edges = in_sizes[2];
    const int n_u     = in_sizes[5];
    const int nbc     = (n_nodes + CMASK) >> CSHIFT;     // 74 for this shape
    const int nsub    = (n_nodes + 63) >> 6;             // 2344

    const size_t ebytes = (size_t)n_edges * 8;           // 80 MB

    const size_t need = 2 * ebytes + ((size_t)n_nodes * 2 + 1) * 4
                      + (MAXC + ((size_t)nbc << 5) + 1024) * 4 + 8192;
    const bool use_main = (ws_size >= need) && (n_nodes < (1 << 21)) && (nbc <= MAXC);

    long n_user4 = (long)n_users * 16;
    long total4  = (long)n_nodes * 16;

    if (use_main) {
        char* w = (char*)d_ws;
        int2* bufA = (int2*)w;       w += ebytes;        // p1 out; final CSR
        int2* bufB = (int2*)w;                           // p2a out; x aliases after p2b
        unsigned short* x_a = (unsigned short*)bufB;
        unsigned short* x_b = x_a + (size_t)n_nodes * 64;
        w += ebytes;
        int* row_ptr  = (int*)w;  w += ((size_t)n_nodes + 1) * 4;
        int* counts   = (int*)w;  w += (size_t)n_nodes * 4;
        int* gcur_c   = (int*)w;  w += MAXC * 4;
        int* gcur_s   = (int*)w;  w += ((size_t)nbc << 5) * 4;
        int* blk_sums = (int*)w;

        // ---- per-node row_ptr ----
        hipMemsetAsync(counts, 0, (size_t)n_nodes * 4, stream);
        hist_kernel<<<2048, 256, 0, stream>>>(edge_dst, counts, n_edges);
        int nblk = (n_nodes + SCAN_BS - 1) / SCAN_BS;    // 586 (<=1024)
        scan_blocks_kernel<<<nblk, SCAN_BS, 0, stream>>>(counts, row_ptr, blk_sums, n_nodes);
        scan_sums_kernel<<<1, 1024, 0, stream>>>(blk_sums, nblk);
        scan_finalize_kernel<<<nblk, SCAN_BS, 0, stream>>>(row_ptr, blk_sums, gcur_c, gcur_s,
                                                           n_nodes, n_edges);
        // ---- 3-level frontier scatter ----
        pass1_kernel<<<(n_edges + P1_CHUNK - 1) / P1_CHUNK, P1_BS, 0, stream>>>(
            edge_src, edge_dst, edge_val, gcur_c, bufA, n_edges, nbc);
        pass2a_kernel<<<nbc * P2A_SEGS, 256, 0, stream>>>(bufA, row_ptr, gcur_s, bufB, n_nodes);
        pass2b_kernel<<<nsub, 256, 0, stream>>>(bufB, row_ptr, bufA, n_nodes);

        // ---- features (bf16) + propagate ----
        concat_bf16_kernel<<<2048, 256, 0, stream>>>((const float4*)user_emb,
                                                     (const float4*)item_emb,
                                                     (ushort4*)x_a, n_user4, total4);
        out_first_kernel<<<n_u, 64, 0, stream>>>(user_emb, u, out);

        unsigned short* cur = x_a;
        unsigned short* nxt = x_b;
        for (int l = 0; l < 3; ++l) {
            spmv_kernel<<<(n_nodes + 3) / 4, 256, 0, stream>>>(cur, nxt, row_ptr, bufA, n_nodes);
            out_accum_kernel<<<n_u, 64, 0, stream>>>(nxt, u, out);
            unsigned short* t = cur; cur = nxt; nxt = t;
        }
    } else {
        const size_t xbytes = (size_t)n_nodes * 64 * 4;
        char* w = (char*)d_ws;
        float* x_a = (float*)w; w += xbytes;
        float* x_b = (float*)w;
        concat_kernel<<<2048, 256, 0, stream>>>((const float4*)user_emb, (const float4*)item_emb,
                                                (float4*)x_a, n_user4, total4);
        out_accum_f32_kernel<<<n_u, 64, 0, stream>>>(x_a, u, out, 1);
        float* cur = x_a;
        float* nxt = x_b;
        for (int l = 0; l < 3; ++l) {
            hipMemsetAsync(nxt, 0, xbytes, stream);
            spmv_atomic_kernel<<<(n_edges + 3) / 4, 256, 0, stream>>>(cur, nxt, edge_src,
                                                                      edge_dst, edge_val, n_edges);
            out_accum_f32_kernel<<<n_u, 64, 0, stream>>>(nxt, u, out, 0);
            float* t = cur; cur = nxt; nxt = t;
        }
    }
}

// Round 6
// 1092.628 us; speedup vs baseline: 10.9560x; 1.3802x over previous
//
#include <hip/hip_runtime.h>
#include <hip/hip_bf16.h>

// LightGCN R6: no per-node global histogram (R5's hist: 10M device atomics,
// 312MB HBM writeback, 388us). Build = sub-bin LDS hist partials + column
// reduce + scan(2344) + 3-level frontier scatter; pass2b derives per-node
// row_ptr in LDS (count + 64-wide scan) and writes it coalesced.
// SpMV: pair-gather -- lane = ushort2 (2 features), 32 lanes/row, each gather
// instruction fetches TWO edges' rows; halves merged by one shfl_xor(32).

constexpr int SCAN_BS   = 256;
constexpr int CSHIFT    = 11;                 // coarse bin = 2048 nodes
constexpr int CMASK     = (1 << CSHIFT) - 1;
constexpr int MAXC      = 128;                // max coarse bins
constexpr int P1_EPT    = 16;
constexpr int P1_BS     = 256;
constexpr int P1_CHUNK  = P1_BS * P1_EPT;     // 4096 edges/block
constexpr int P2A_SEGS  = 32;
constexpr int STAGE_CAP = 8192;               // 64KB int2 staging (avg subbin ~4.3K)
constexpr int SH_BLOCKS = 256;                // subhist partial blocks

__device__ __forceinline__ unsigned short f2bf(float f) {
    unsigned u = __float_as_uint(f);
    u += 0x7FFFu + ((u >> 16) & 1u);          // round-to-nearest-even
    return (unsigned short)(u >> 16);
}
__device__ __forceinline__ float bf2f(unsigned short us) {
    return __uint_as_float((unsigned)us << 16);
}

__global__ void concat_bf16_kernel(const float4* __restrict__ ue, const float4* __restrict__ ie,
                                   ushort4* __restrict__ x, long n_user4, long total4) {
    long i = (long)blockIdx.x * blockDim.x + threadIdx.x;
    long stride = (long)gridDim.x * blockDim.x;
    for (; i < total4; i += stride) {
        float4 v = (i < n_user4) ? ue[i] : ie[i - n_user4];
        ushort4 o;
        o.x = f2bf(v.x); o.y = f2bf(v.y); o.z = f2bf(v.z); o.w = f2bf(v.w);
        x[i] = o;
    }
}

// Sub-bin histogram partials: LDS hist (nsub counters), each block writes its
// private row of hist_part -- zero global atomics.
__global__ void subhist_kernel(const int* __restrict__ dst, int* __restrict__ hist_part,
                               int n, int nsub) {
    extern __shared__ int lh[];
    for (int j = threadIdx.x; j < nsub; j += blockDim.x) lh[j] = 0;
    __syncthreads();
    int i = blockIdx.x * blockDim.x + threadIdx.x;
    int stride = gridDim.x * blockDim.x;
    for (; i < n; i += stride) atomicAdd(&lh[dst[i] >> 6], 1);
    __syncthreads();
    int* myrow = hist_part + (size_t)blockIdx.x * nsub;
    for (int j = threadIdx.x; j < nsub; j += blockDim.x) myrow[j] = lh[j];
}

__global__ void reduce_hist_kernel(const int* __restrict__ hist_part,
                                   int* __restrict__ sub_counts, int nsub) {
    int j = blockIdx.x * blockDim.x + threadIdx.x;
    if (j >= nsub) return;
    int s = 0;
    for (int b = 0; b < SH_BLOCKS; ++b) s += hist_part[(size_t)b * nsub + j];
    sub_counts[j] = s;
}

__global__ void scan_blocks_kernel(const int* __restrict__ counts, int* __restrict__ base,
                                   int* __restrict__ blk_sums, int n) {
    __shared__ int tmp[SCAN_BS];
    int tid = threadIdx.x;
    int i = blockIdx.x * SCAN_BS + tid;
    int v = (i < n) ? counts[i] : 0;
    tmp[tid] = v;
    __syncthreads();
    for (int off = 1; off < SCAN_BS; off <<= 1) {
        int t = (tid >= off) ? tmp[tid - off] : 0;
        __syncthreads();
        tmp[tid] += t;
        __syncthreads();
    }
    if (i < n) base[i] = tmp[tid] - v;             // exclusive
    if (tid == SCAN_BS - 1) blk_sums[blockIdx.x] = tmp[tid];
}

__global__ void scan_sums_kernel(int* blk_sums, int nblk) {
    __shared__ int tmp[1024];
    int tid = threadIdx.x;
    int v = (tid < nblk) ? blk_sums[tid] : 0;
    tmp[tid] = v;
    __syncthreads();
    for (int off = 1; off < 1024; off <<= 1) {
        int t = (tid >= off) ? tmp[tid - off] : 0;
        __syncthreads();
        tmp[tid] += t;
        __syncthreads();
    }
    if (tid < nblk) blk_sums[tid] = tmp[tid] - v;  // exclusive
}

// Finalize sub-bin bases; also seed coarse-bin and sub-bin frontier cursors.
__global__ void scan_finalize_sub_kernel(int* __restrict__ sub_base,
                                         const int* __restrict__ blk_sums,
                                         int* __restrict__ gcur_c, int* __restrict__ gcur_s,
                                         int n, int n_edges) {
    int i = blockIdx.x * SCAN_BS + threadIdx.x;
    if (i < n) {
        int r = sub_base[i] + blk_sums[blockIdx.x];
        sub_base[i] = r;
        gcur_s[i] = r;
        if ((i & 31) == 0) gcur_c[i >> 5] = r;
    }
    if (i == 0) sub_base[n] = n_edges;
}

// Pass 1: counting scatter into coarse bins; block-local LDS hist -> one global
// atomic per (block,bin); chunk writes (~440B) advance 74 frontiers.
__global__ __launch_bounds__(P1_BS) void pass1_kernel(
        const int* __restrict__ src, const int* __restrict__ dst,
        const float* __restrict__ val, int* gcur_c, int2* __restrict__ bufA,
        int n, int nbc) {
    __shared__ int lh[MAXC];
    __shared__ int lbase[MAXC];
    int tid = threadIdx.x;
    int base = blockIdx.x * P1_CHUNK;
    for (int j = tid; j < nbc; j += P1_BS) lh[j] = 0;
    __syncthreads();
    int dreg[P1_EPT], rreg[P1_EPT];
#pragma unroll
    for (int k = 0; k < P1_EPT; ++k) {
        int i = base + k * P1_BS + tid;
        if (i < n) {
            int d = dst[i];
            dreg[k] = d;
            rreg[k] = atomicAdd(&lh[d >> CSHIFT], 1);
        } else dreg[k] = -1;
    }
    __syncthreads();
    for (int j = tid; j < nbc; j += P1_BS) {
        int c = lh[j];
        lbase[j] = c ? atomicAdd(&gcur_c[j], c) : 0;
    }
    __syncthreads();
#pragma unroll
    for (int k = 0; k < P1_EPT; ++k) {
        int d = dreg[k];
        if (d >= 0) {
            int i = base + k * P1_BS + tid;
            int p = lbase[d >> CSHIFT] + rreg[k];
            bufA[p] = make_int2(src[i] | ((d & CMASK) << 21), __float_as_int(val[i]));
        }
    }
}

// Pass 2a: coarse bin -> 32 sub-bins of 64 nodes. Per-segment LDS hist, global
// frontier claim, ~1KB chunk writes at 2368 frontiers.
__global__ __launch_bounds__(256) void pass2a_kernel(
        const int2* __restrict__ bufA, const int* __restrict__ sub_base,
        int* gcur_s, int2* __restrict__ bufB, int nsub) {
    __shared__ int lh[32], lbase[32], lrank[32];
    int bin = blockIdx.x >> 5;
    int seg = blockIdx.x & (P2A_SEGS - 1);
    int tid = threadIdx.x;
    int sb0 = bin << 5;
    int sb1 = min(sb0 + 32, nsub);
    int e0 = sub_base[sb0], e1 = sub_base[sb1];
    int len = e1 - e0;
    int s0 = e0 + (int)((long)len * seg / P2A_SEGS);
    int s1 = e0 + (int)((long)len * (seg + 1) / P2A_SEGS);
    if (tid < 32) { lh[tid] = 0; lrank[tid] = 0; }
    __syncthreads();
#pragma unroll 4
    for (int i = s0 + tid; i < s1; i += 256)
        atomicAdd(&lh[((unsigned)bufA[i].x >> 21) >> 6], 1);
    __syncthreads();
    if (tid < 32) {
        int c = lh[tid];
        lbase[tid] = c ? atomicAdd(&gcur_s[sb0 + tid], c) : 0;
    }
    __syncthreads();
#pragma unroll 4
    for (int i = s0 + tid; i < s1; i += 256) {
        int2 q = bufA[i];                       // second read: L2-hot
        int j = ((unsigned)q.x >> 21) >> 6;
        int p = lbase[j] + atomicAdd(&lrank[j], 1);
        bufB[p] = q;
    }
}

// Pass 2b: one block per 64-node sub-bin. Count per-node in LDS, 64-wide scan
// -> per-node row_ptr (written coalesced) + LDS cursors; rank edges into LDS
// staging; flush coalesced. Zero write inflation, no global per-node hist.
__global__ __launch_bounds__(256) void pass2b_kernel(
        const int2* __restrict__ bufB, const int* __restrict__ sub_base,
        int* __restrict__ row_ptr, int2* __restrict__ csr, int n_nodes, int n_edges) {
    __shared__ int2 stage[STAGE_CAP];
    __shared__ int cnt[64], incl[64];
    int b = blockIdx.x;
    int tid = threadIdx.x;
    int node0 = b << 6;
    int e0 = sub_base[b];
    int e1 = sub_base[b + 1];
    if (tid < 64) cnt[tid] = 0;
    __syncthreads();
#pragma unroll 4
    for (int i = e0 + tid; i < e1; i += 256)
        atomicAdd(&cnt[((unsigned)bufB[i].x >> 21) & 63], 1);
    __syncthreads();
    if (tid < 64) incl[tid] = cnt[tid];
    __syncthreads();
    for (int off = 1; off < 64; off <<= 1) {
        int t = (tid < 64 && tid >= off) ? incl[tid - off] : 0;
        __syncthreads();
        if (tid < 64) incl[tid] += t;
        __syncthreads();
    }
    if (tid < 64) {
        int ex = incl[tid] - cnt[tid];
        cnt[tid] = ex;                          // becomes rank cursor
        int node = node0 + tid;
        if (node < n_nodes) row_ptr[node] = e0 + ex;
    }
    if (b == 0 && tid == 0) row_ptr[n_nodes] = n_edges;
    __syncthreads();
#pragma unroll 4
    for (int i = e0 + tid; i < e1; i += 256) {
        int2 q = bufB[i];                       // second read: L2-hot
        int nl = ((unsigned)q.x >> 21) & 63;
        int r = atomicAdd(&cnt[nl], 1);
        int2 v = make_int2(q.x & 0x1FFFFF, q.y);
        if (r < STAGE_CAP) stage[r] = v;
        else csr[(size_t)e0 + r] = v;           // overflow fallback (rare)
    }
    __syncthreads();
    int lim = min(e1 - e0, STAGE_CAP);
    for (int i = tid; i < lim; i += 256)
        csr[(size_t)e0 + i] = stage[i];
}

// Pair-gather spmv: one wave per node. lane&31 = feature pair (2f,2f+1) as
// ushort2/u32; lane>>5 = which edge of a pair. Each gather instruction fetches
// two edges' 128B rows. Main loop: 16 edges/iter = 8 gathers in flight.
__global__ __launch_bounds__(256) void spmv_kernel(
        const unsigned short* __restrict__ x, unsigned short* __restrict__ y,
        const int* __restrict__ row_ptr, const int2* __restrict__ csr, int n_nodes) {
    const unsigned* xw = (const unsigned*)x;
    int lane = threadIdx.x & 63;
    int h    = lane >> 5;                      // 0: even edge, 1: odd edge
    int fl   = lane & 31;                      // feature pair index
    int node = blockIdx.x * 4 + (threadIdx.x >> 6);
    if (node >= n_nodes) return;
    int e0 = row_ptr[node];
    int e1 = row_ptr[node + 1];
    float a0l = 0.f, a0h = 0.f, a1l = 0.f, a1h = 0.f;
    float a2l = 0.f, a2h = 0.f, a3l = 0.f, a3h = 0.f;
    int e = e0;
    for (; e + 16 <= e1; e += 16) {
        int2 q0 = csr[e + 0 + h];
        int2 q1 = csr[e + 2 + h];
        int2 q2 = csr[e + 4 + h];
        int2 q3 = csr[e + 6 + h];
        int2 q4 = csr[e + 8 + h];
        int2 q5 = csr[e + 10 + h];
        int2 q6 = csr[e + 12 + h];
        int2 q7 = csr[e + 14 + h];
        unsigned g0 = xw[(unsigned)q0.x * 32 + fl];
        unsigned g1 = xw[(unsigned)q1.x * 32 + fl];
        unsigned g2 = xw[(unsigned)q2.x * 32 + fl];
        unsigned g3 = xw[(unsigned)q3.x * 32 + fl];
        unsigned g4 = xw[(unsigned)q4.x * 32 + fl];
        unsigned g5 = xw[(unsigned)q5.x * 32 + fl];
        unsigned g6 = xw[(unsigned)q6.x * 32 + fl];
        unsigned g7 = xw[(unsigned)q7.x * 32 + fl];
        float v0 = __int_as_float(q0.y), v1 = __int_as_float(q1.y);
        float v2 = __int_as_float(q2.y), v3 = __int_as_float(q3.y);
        float v4 = __int_as_float(q4.y), v5 = __int_as_float(q5.y);
        float v6 = __int_as_float(q6.y), v7 = __int_as_float(q7.y);
        a0l = fmaf(v0, __uint_as_float(g0 << 16), a0l);
        a0h = fmaf(v0, __uint_as_float(g0 & 0xFFFF0000u), a0h);
        a1l = fmaf(v1, __uint_as_float(g1 << 16), a1l);
        a1h = fmaf(v1, __uint_as_float(g1 & 0xFFFF0000u), a1h);
        a2l = fmaf(v2, __uint_as_float(g2 << 16), a2l);
        a2h = fmaf(v2, __uint_as_float(g2 & 0xFFFF0000u), a2h);
        a3l = fmaf(v3, __uint_as_float(g3 << 16), a3l);
        a3h = fmaf(v3, __uint_as_float(g3 & 0xFFFF0000u), a3h);
        a0l = fmaf(v4, __uint_as_float(g4 << 16), a0l);
        a0h = fmaf(v4, __uint_as_float(g4 & 0xFFFF0000u), a0h);
        a1l = fmaf(v5, __uint_as_float(g5 << 16), a1l);
        a1h = fmaf(v5, __uint_as_float(g5 & 0xFFFF0000u), a1h);
        a2l = fmaf(v6, __uint_as_float(g6 << 16), a2l);
        a2h = fmaf(v6, __uint_as_float(g6 & 0xFFFF0000u), a2h);
        a3l = fmaf(v7, __uint_as_float(g7 << 16), a3l);
        a3h = fmaf(v7, __uint_as_float(g7 & 0xFFFF0000u), a3h);
    }
    for (; e + 2 <= e1; e += 2) {
        int2 q = csr[e + h];
        float v = __int_as_float(q.y);
        unsigned g = xw[(unsigned)q.x * 32 + fl];
        a0l = fmaf(v, __uint_as_float(g << 16), a0l);
        a0h = fmaf(v, __uint_as_float(g & 0xFFFF0000u), a0h);
    }
    if (e < e1) {                               // single leftover edge: half 0 only
        int2 q = csr[e];
        float v = (h == 0) ? __int_as_float(q.y) : 0.f;
        unsigned g = xw[(unsigned)q.x * 32 + fl];
        a0l = fmaf(v, __uint_as_float(g << 16), a0l);
        a0h = fmaf(v, __uint_as_float(g & 0xFFFF0000u), a0h);
    }
    float sl = (a0l + a1l) + (a2l + a3l);
    float sh = (a0h + a1h) + (a2h + a3h);
    sl += __shfl_xor(sl, 32);                   // merge even/odd-edge halves
    sh += __shfl_xor(sh, 32);
    if (lane < 32) {
        unsigned packed = (unsigned)f2bf(sl) | ((unsigned)f2bf(sh) << 16);
        ((unsigned*)y)[(unsigned)node * 32 + fl] = packed;
    }
}

__global__ void out_first_kernel(const float* __restrict__ ue, const int* __restrict__ u,
                                 float* __restrict__ out) {
    int i = blockIdx.x;
    int lane = threadIdx.x;
    out[(size_t)i * 64 + lane] = 0.25f * ue[(size_t)u[i] * 64 + lane];
}

__global__ void out_accum_kernel(const unsigned short* __restrict__ x, const int* __restrict__ u,
                                 float* __restrict__ out) {
    int i = blockIdx.x;
    int lane = threadIdx.x;
    out[(size_t)i * 64 + lane] += 0.25f * bf2f(x[((unsigned)u[i] << 6) + lane]);
}

// ---- f32 fallback path (tiny ws) ----
__global__ void concat_kernel(const float4* __restrict__ ue, const float4* __restrict__ ie,
                              float4* __restrict__ x, long n_user4, long total4) {
    long i = (long)blockIdx.x * blockDim.x + threadIdx.x;
    long stride = (long)gridDim.x * blockDim.x;
    for (; i < total4; i += stride)
        x[i] = (i < n_user4) ? ue[i] : ie[i - n_user4];
}
__global__ void spmv_atomic_kernel(const float* __restrict__ x, float* y,
                                   const int* __restrict__ src, const int* __restrict__ dst,
                                   const float* __restrict__ val, int n_edges) {
    int lane = threadIdx.x & 63;
    int e = blockIdx.x * (blockDim.x >> 6) + (threadIdx.x >> 6);
    if (e >= n_edges) return;
    float v = val[e];
    atomicAdd(&y[(size_t)dst[e] * 64 + lane], v * x[(size_t)src[e] * 64 + lane]);
}
__global__ void out_accum_f32_kernel(const float* __restrict__ x, const int* __restrict__ u,
                                     float* __restrict__ out, int first) {
    int i = blockIdx.x;
    int lane = threadIdx.x;
    float v = 0.25f * x[(size_t)u[i] * 64 + lane];
    if (first) out[(size_t)i * 64 + lane] = v;
    else       out[(size_t)i * 64 + lane] += v;
}

extern "C" void kernel_launch(void* const* d_in, const int* in_sizes, int n_in,
                              void* d_out, int out_size, void* d_ws, size_t ws_size,
                              hipStream_t stream) {
    const float* user_emb = (const float*)d_in[0];
    const float* item_emb = (const float*)d_in[1];
    const int*   edge_src = (const int*)d_in[2];
    const int*   edge_dst = (const int*)d_in[3];
    const float* edge_val = (const float*)d_in[4];
    const int*   u        = (const int*)d_in[5];
    float* out = (float*)d_out;

    const int n_users = in_sizes[0] / 64;
    const int n_items = in_sizes[1] / 64;
    const int n_nodes = n_users + n_items;
    const int n_edges = in_sizes[2];
    const int n_u     = in_sizes[5];
    const int nbc     = (n_nodes + CMASK) >> CSHIFT;     // 74 for this shape
    const int nsub    = (n_nodes + 63) >> 6;             // 2344

    const size_t ebytes = (size_t)n_edges * 8;           // 80 MB

    const size_t need = 2 * ebytes
                      + ((size_t)nsub * 3 + 1 + MAXC + 1024 + (size_t)n_nodes + 1) * 4
                      + 8192;
    const bool use_main = (ws_size >= need) && (n_nodes < (1 << 21)) && (nbc <= MAXC)
                        && ((size_t)SH_BLOCKS * nsub * 4 <= ebytes)
                        && ((size_t)n_nodes * 256 <= ebytes);   // x_a/x_b fit in bufB

    long n_user4 = (long)n_users * 16;
    long total4  = (long)n_nodes * 16;

    if (use_main) {
        char* w = (char*)d_ws;
        int2* bufA = (int2*)w;       w += ebytes;        // p1 out; final CSR
        int2* bufB = (int2*)w;       w += ebytes;        // p2a out; x aliases after p2b
        unsigned short* x_a = (unsigned short*)bufB;
        unsigned short* x_b = x_a + (size_t)n_nodes * 64;
        int* hist_part  = (int*)bufA;                    // dead before pass1 writes
        int* sub_counts = (int*)w;  w += (size_t)nsub * 4;
        int* sub_base   = (int*)w;  w += ((size_t)nsub + 1) * 4;
        int* gcur_c     = (int*)w;  w += MAXC * 4;
        int* gcur_s     = (int*)w;  w += (size_t)nsub * 4;
        int* blk_sums   = (int*)w;  w += 1024 * 4;
        int* row_ptr    = (int*)w;  w += ((size_t)n_nodes + 1) * 4;

        // ---- sub-bin counts (no global atomics) + scan ----
        subhist_kernel<<<SH_BLOCKS, 256, (size_t)nsub * 4, stream>>>(edge_dst, hist_part,
                                                                     n_edges, nsub);
        reduce_hist_kernel<<<(nsub + 255) / 256, 256, 0, stream>>>(hist_part, sub_counts, nsub);
        int nblk = (nsub + SCAN_BS - 1) / SCAN_BS;       // 10
        scan_blocks_kernel<<<nblk, SCAN_BS, 0, stream>>>(sub_counts, sub_base, blk_sums, nsub);
        scan_sums_kernel<<<1, 1024, 0, stream>>>(blk_sums, nblk);
        scan_finalize_sub_kernel<<<nblk, SCAN_BS, 0, stream>>>(sub_base, blk_sums, gcur_c,
                                                               gcur_s, nsub, n_edges);
        // ---- 3-level frontier scatter (also emits row_ptr in pass2b) ----
        pass1_kernel<<<(n_edges + P1_CHUNK - 1) / P1_CHUNK, P1_BS, 0, stream>>>(
            edge_src, edge_dst, edge_val, gcur_c, bufA, n_edges, nbc);
        pass2a_kernel<<<nbc * P2A_SEGS, 256, 0, stream>>>(bufA, sub_base, gcur_s, bufB, nsub);
        pass2b_kernel<<<nsub, 256, 0, stream>>>(bufB, sub_base, row_ptr, bufA,
                                                n_nodes, n_edges);

        // ---- features (bf16; x aliases bufB, safe after pass2b) + propagate ----
        concat_bf16_kernel<<<2048, 256, 0, stream>>>((const float4*)user_emb,
                                                     (const float4*)item_emb,
                                                     (ushort4*)x_a, n_user4, total4);
        out_first_kernel<<<n_u, 64, 0, stream>>>(user_emb, u, out);

        unsigned short* cur = x_a;
        unsigned short* nxt = x_b;
        for (int l = 0; l < 3; ++l) {
            spmv_kernel<<<(n_nodes + 3) / 4, 256, 0, stream>>>(cur, nxt, row_ptr, bufA, n_nodes);
            out_accum_kernel<<<n_u, 64, 0, stream>>>(nxt, u, out);
            unsigned short* t = cur; cur = nxt; nxt = t;
        }
    } else {
        const size_t xbytes = (size_t)n_nodes * 64 * 4;
        char* w = (char*)d_ws;
        float* x_a = (float*)w; w += xbytes;
        float* x_b = (float*)w;
        concat_kernel<<<2048, 256, 0, stream>>>((const float4*)user_emb, (const float4*)item_emb,
                                                (float4*)x_a, n_user4, total4);
        out_accum_f32_kernel<<<n_u, 64, 0, stream>>>(x_a, u, out, 1);
        float* cur = x_a;
        float* nxt = x_b;
        for (int l = 0; l < 3; ++l) {
            hipMemsetAsync(nxt, 0, xbytes, stream);
            spmv_atomic_kernel<<<(n_edges + 3) / 4, 256, 0, stream>>>(cur, nxt, edge_src,
                                                                      edge_dst, edge_val, n_edges);
            out_accum_f32_kernel<<<n_u, 64, 0, stream>>>(nxt, u, out, 0);
            float* t = cur; cur = nxt; nxt = t;
        }
    }
}